// Round 10
// baseline (323.491 us; speedup 1.0000x reference)
//
#include <hip/hip_runtime.h>
#include <cstddef>

// D,H,W,C = 10,200,176,64; convs: (s2,p1) -> (s1,p(0,1,1)) -> (s2,p1)
// Activations channels-last fp16, pixel = 128 B, CHUNK-SWIZZLED within pixel:
//   16B chunk s of pixel at column P stored at position s ^ (P & 7).
// Verbatim global_load_lds staging then gives conflict-free MFMA fragment reads.
// Weights: plain [tap][co][ci] fp16, read per-tap straight from L1/L2 (NO LDS,
// only 8 fragments = 32 VGPR live at a time - the r9 spill fix).
#define HH 200
#define WW 176
#define HP 202
#define WP 178
#define D_IN 10
#define D1 5
#define D2 3
#define D3 2
#define SLICE ((size_t)HP * WP * 64)

typedef _Float16 h8 __attribute__((ext_vector_type(8)));
typedef float f4 __attribute__((ext_vector_type(4)));

__device__ __forceinline__ void gl_lds16(const void* g, void* l) {
    __builtin_amdgcn_global_load_lds(
        (const __attribute__((address_space(1))) void*)g,
        (__attribute__((address_space(3))) void*)l, 16, 0, 0);
}

// ---- prep: halo-zero A2/A3 + weight transform (3 sets) + winner, one launch
// blocks [0,8): halo; [8, 8+1296): wtrans; [1304, ...): winner
__global__ __launch_bounds__(256) void prep_k(const float* __restrict__ W1,
                                              const float* __restrict__ W2,
                                              const float* __restrict__ W3,
                                              _Float16* __restrict__ wdst,
                                              _Float16* __restrict__ A2,
                                              _Float16* __restrict__ A3,
                                              const int* __restrict__ coors,
                                              int* __restrict__ winner, int nvox) {
    const int b = blockIdx.x;
    if (b < 8) {
        _Float16* base = (b < D1) ? (A2 + (size_t)b * SLICE) : (A3 + (size_t)(b - D1) * SLICE);
        const h8 z = {};
        for (int t = threadIdx.x; t < 6080; t += 256) {
            size_t off;
            if (t < 2848) {
                int r = t / 1424, c = t - r * 1424;
                off = (size_t)(r ? (HP - 1) : 0) * WP * 64 + (size_t)c * 8;
            } else {
                int u = t - 2848;
                int c = u / 1616, v = u - c * 1616;
                int hr = v >> 3, o = v & 7;
                off = ((size_t)hr * WP + (c ? (WP - 1) : 0)) * 64 + (size_t)o * 8;
            }
            *(h8*)(base + off) = z;
        }
    } else if (b < 8 + 1296) {
        // OIDHW fp32 -> [set][tap][co][ci] fp16 (plain: B is read from global)
        int idx = (b - 8) * 256 + threadIdx.x;
        if (idx < 3 * 27 * 64 * 64) {
            int set = idx / 110592;
            int r = idx - set * 110592;
            const float* src = set == 0 ? W1 : (set == 1 ? W2 : W3);
            int ci = r & 63;
            int co = (r >> 6) & 63;
            int tap = r >> 12;
            wdst[set * 110592 + tap * 4096 + co * 64 + ci] =
                (_Float16)src[(co * 64 + ci) * 27 + tap];
        }
    } else {
        int v = (b - 1304) * 256 + threadIdx.x;
        if (v < nvox) {
            int d = coors[v * 4 + 1], h = coors[v * 4 + 2], w = coors[v * 4 + 3];
            atomicMax(&winner[(d * HH + h) * WW + w], v + 1);
        }
    }
}

__global__ __launch_bounds__(256) void scatter_k(const float* __restrict__ feat,
                                                 const int* __restrict__ coors,
                                                 const int* __restrict__ winner,
                                                 _Float16* __restrict__ A, int nvox) {
    int v = blockIdx.x * 4 + (threadIdx.x >> 6);
    int ci = threadIdx.x & 63;
    if (v >= nvox) return;
    int d = coors[v * 4 + 1], h = coors[v * 4 + 2], w = coors[v * 4 + 3];
    if (winner[(d * HH + h) * WW + w] != v + 1) return;
    int P = w + 1;
    int swz = (((ci >> 3) ^ (P & 7)) << 3) | (ci & 7);
    A[(size_t)d * SLICE + ((size_t)(h + 1) * WP + P) * 64 + swz] = (_Float16)feat[v * 64 + ci];
}

// ---------------- MFMA conv: A in LDS (only), B from L1/L2 -----------------
// Block = NW waves; wave i -> output row h0+i, 48 px (mt=3), 64 co (nt=4).
// Per kd: stage A (NW+2 rows x 50 px) via global_load_lds, 2 barriers, then
// 9 taps x 6 K32-steps. B-frags: 8 per tap (32 VGPR) loaded from the L1-hot
// plain weight array inside a #pragma unroll 1 tap loop (no r9 hoist/spill).
// LDS 38,912 B (NW=4) -> 4 blocks/CU = 16 waves; launch_bounds(.,4) caps VGPR 128.
// mfma_f32_16x16x32_f16: A[m=lane&15][k=quad*8+j], D: co=lane&15, px=quad*4+reg
template <int NW, int FINAL>
__global__ __launch_bounds__(NW * 64, 4) void conv_mfma_k(
    const _Float16* __restrict__ in, void* __restrict__ outp,
    const _Float16* __restrict__ wt,
    const float* __restrict__ scale, const float* __restrict__ bias,
    int inD, int strideD, int padD) {
    __shared__ char smem_raw[(NW + 2) * 50 * 128 + 512];
    _Float16* la = (_Float16*)smem_raw;

    const int lane = threadIdx.x & 63;
    const int wave = threadIdx.x >> 6;   // 0..NW-1
    const int l16 = lane & 15;
    const int quad = lane >> 4;
    const int h0 = blockIdx.y * NW;
    const int wb = blockIdx.x * 48;      // 48 | 8 so (wb+px)&7 == px&7
    const int d = blockIdx.z;

    int kd_lo = padD - d * strideD; if (kd_lo < 0) kd_lo = 0;
    int kd_hi = inD - 1 - d * strideD + padD; if (kd_hi > 2) kd_hi = 2;

    f4 acc[3][4];
#pragma unroll
    for (int mt = 0; mt < 3; ++mt)
#pragma unroll
        for (int nt = 0; nt < 4; ++nt) acc[mt][nt] = (f4){0.f, 0.f, 0.f, 0.f};

    for (int kd = kd_lo; kd <= kd_hi; ++kd) {
        const int zd = d * strideD + kd - padD;
        const _Float16* __restrict__ aplane = in + (size_t)zd * SLICE;

        __syncthreads();  // previous kd's LDS reads complete
        // stage A: (NW+2) rows x 50 px x 8 chunks via glds (verbatim, swizzled)
        constexpr int NCH = (NW + 2) * 400;
        constexpr int NI = (NCH + 63) >> 6;
        for (int j = wave; j < NI; j += NW) {
            int c = j * 64 + lane;
            if (c > NCH - 1) c = NCH - 1;          // dup last chunk into pad
            int r = c / 400;
            int rem = c - r * 400;
            int px = rem >> 3, s = rem & 7;
            int g = wb + px; if (g > 177) g = 177;  // ragged edge: dup col
            gl_lds16(aplane + ((size_t)(h0 + r) * WP + g) * 64 + s * 8,
                     smem_raw + j * 1024);
        }
        __syncthreads();  // drains vmcnt: staged data visible

        const _Float16* __restrict__ wkd = wt + (size_t)kd * 9 * 4096;
#pragma unroll 1
        for (int t = 0; t < 9; ++t) {   // tap = kh*3+kw; unroll 1 = hoist wall
            const int kh = t / 3;
            const int kw = t - 3 * kh;
            const _Float16* __restrict__ wp = wkd + t * 4096;
            h8 b[2][4];                  // 32 VGPR live
#pragma unroll
            for (int ch = 0; ch < 2; ++ch) {
                const int q = ch * 4 + quad;
#pragma unroll
                for (int nt = 0; nt < 4; ++nt)
                    b[ch][nt] = *(const h8*)(wp + (nt * 16 + l16) * 64 + q * 8);
            }
#pragma unroll
            for (int ch = 0; ch < 2; ++ch) {
                const int q = ch * 4 + quad;
#pragma unroll
                for (int mt = 0; mt < 3; ++mt) {
                    const int px = mt * 16 + l16 + kw;
                    h8 a = *(const h8*)(la + ((wave + kh) * 50 + px) * 64 +
                                        ((q ^ (px & 7)) << 3));
#pragma unroll
                    for (int nt = 0; nt < 4; ++nt)
                        acc[mt][nt] = __builtin_amdgcn_mfma_f32_16x16x32_f16(
                            a, b[ch][nt], acc[mt][nt], 0, 0, 0);
                }
            }
        }
    }

    // epilogue: scale+bias+relu; D layout: co=l16(+nt*16), px=mt*16+quad*4+reg
    const int h = h0 + wave;
#pragma unroll
    for (int nt = 0; nt < 4; ++nt) {
        const int co = nt * 16 + l16;
        const float s = scale[co];
        const float bb = bias[co];
#pragma unroll
        for (int mt = 0; mt < 3; ++mt) {
            const int w0 = wb + mt * 16 + quad * 4;  // multiple of 4
            if (w0 < WW) {
                if (FINAL) {
                    f4 v;
#pragma unroll
                    for (int r = 0; r < 4; ++r) {
                        float x = acc[mt][nt][r] * s + bb;
                        v[r] = x > 0.f ? x : 0.f;
                    }
                    *(f4*)((float*)outp + (((size_t)(co * 2 + d)) * HH + h) * WW + w0) = v;
                } else {
#pragma unroll
                    for (int r = 0; r < 4; ++r) {
                        float x = acc[mt][nt][r] * s + bb;
                        x = x > 0.f ? x : 0.f;
                        const int P = w0 + r + 1;
                        const int swz = (((co >> 3) ^ (P & 7)) << 3) | (co & 7);
                        ((_Float16*)outp)[(size_t)d * SLICE +
                            ((size_t)(h + 1) * WP + P) * 64 + swz] = (_Float16)x;
                    }
                }
            }
        }
    }
}

// ---------------- launch ---------------------------------------------------
extern "C" void kernel_launch(void* const* d_in, const int* in_sizes, int n_in,
                              void* d_out, int out_size, void* d_ws, size_t ws_size,
                              hipStream_t stream) {
    const float* feat   = (const float*)d_in[0];
    const int*   coors  = (const int*)d_in[1];
    const float* W1     = (const float*)d_in[3];
    const float* scale1 = (const float*)d_in[4];
    const float* bias1  = (const float*)d_in[5];
    const float* W2     = (const float*)d_in[6];
    const float* scale2 = (const float*)d_in[7];
    const float* bias2  = (const float*)d_in[8];
    const float* W3     = (const float*)d_in[9];
    const float* scale3 = (const float*)d_in[10];
    const float* bias3  = (const float*)d_in[11];
    const int nvox = in_sizes[0] / 64;

    // workspace: [A1][win][A2][A3][wt x3]; memset covers A1+win only
    const size_t nA1 = (size_t)D_IN * SLICE;     // fp16 elems
    const size_t nWin = (size_t)D_IN * HH * WW;  // ints
    const size_t nA2 = (size_t)D1 * SLICE;
    const size_t nA3 = (size_t)D2 * SLICE;
    const size_t nWT = (size_t)27 * 64 * 64;     // fp16 elems per set

    _Float16* A1 = (_Float16*)d_ws;
    int* win = (int*)(A1 + nA1);
    _Float16* A2 = (_Float16*)(win + nWin);
    _Float16* A3 = A2 + nA2;
    _Float16* wt1 = A3 + nA3;
    _Float16* wt2 = wt1 + nWT;
    _Float16* wt3 = wt2 + nWT;

    hipMemsetAsync(d_ws, 0, nA1 * sizeof(_Float16) + nWin * sizeof(int), stream);

    const int win_blk = (nvox + 255) / 256;
    prep_k<<<8 + 1296 + win_blk, 256, 0, stream>>>(W1, W2, W3, wt1, A2, A3,
                                                   coors, win, nvox);
    scatter_k<<<(nvox + 3) / 4, 256, 0, stream>>>(feat, coors, win, A1, nvox);

    // conv1: A1(10) -> A2(5); NW=4 -> 1000 blocks @ 4/CU (97% fill)
    conv_mfma_k<4, 0><<<dim3(4, 50, D1), 256, 0, stream>>>(A1, A2, wt1, scale1, bias1, D_IN, 2, 1);
    // conv2: A2(5) -> A3(3); NW=2 -> 1200 blocks @ 6/CU (94% fill)
    conv_mfma_k<2, 0><<<dim3(4, 100, D2), 128, 0, stream>>>(A2, A3, wt2, scale2, bias2, D1, 1, 0);
    // conv3: A3(3) -> out planar fp32; NW=2 -> 800 blocks
    conv_mfma_k<2, 1><<<dim3(4, 100, D3), 128, 0, stream>>>(A3, (float*)d_out, wt3, scale3, bias3, D2, 2, 1);
}

// Round 11
// 197.030 us; speedup vs baseline: 1.6418x; 1.6418x over previous
//
#include <hip/hip_runtime.h>
#include <cstddef>

// D,H,W,C = 10,200,176,64; convs: (s2,p1) -> (s1,p(0,1,1)) -> (s2,p1)
// Activations channels-last fp16, pixel = 128 B, CHUNK-SWIZZLED within pixel:
//   16B chunk s of pixel at column P stored at position s ^ (P & 7).
// Verbatim global_load_lds staging then gives conflict-free MFMA fragment reads.
// Weights pre-swizzled by co: chunk s of row co stored at s ^ (co & 7).
#define HH 200
#define WW 176
#define HP 202
#define WP 178
#define D_IN 10
#define D1 5
#define D2 3
#define D3 2
#define SLICE ((size_t)HP * WP * 64)

// LDS: A 6 rows x 50 px x 128 B = 38,400 (+512 overrun pad) + B ONE tap 8,192
//    = 47,104 <= 49,152 (3 x 16KB granules) -> 3 blocks/CU = 12 waves (r11 fix)
#define LA_BYTES 38912
#define LDS_TOTAL (38912 + 8192)

typedef _Float16 h8 __attribute__((ext_vector_type(8)));
typedef float f4 __attribute__((ext_vector_type(4)));

__device__ __forceinline__ void gl_lds16(const void* g, void* l) {
    __builtin_amdgcn_global_load_lds(
        (const __attribute__((address_space(1))) void*)g,
        (__attribute__((address_space(3))) void*)l, 16, 0, 0);
}

// ---- prep: halo-zero A2/A3 + weight transform (3 sets) + winner, one launch
// blocks [0,8): halo; [8, 8+1296): wtrans; [1304, ...): winner
__global__ __launch_bounds__(256) void prep_k(const float* __restrict__ W1,
                                              const float* __restrict__ W2,
                                              const float* __restrict__ W3,
                                              _Float16* __restrict__ wdst,
                                              _Float16* __restrict__ A2,
                                              _Float16* __restrict__ A3,
                                              const int* __restrict__ coors,
                                              int* __restrict__ winner, int nvox) {
    const int b = blockIdx.x;
    if (b < 8) {
        _Float16* base = (b < D1) ? (A2 + (size_t)b * SLICE) : (A3 + (size_t)(b - D1) * SLICE);
        const h8 z = {};
        for (int t = threadIdx.x; t < 6080; t += 256) {
            size_t off;
            if (t < 2848) {
                int r = t / 1424, c = t - r * 1424;
                off = (size_t)(r ? (HP - 1) : 0) * WP * 64 + (size_t)c * 8;
            } else {
                int u = t - 2848;
                int c = u / 1616, v = u - c * 1616;
                int hr = v >> 3, o = v & 7;
                off = ((size_t)hr * WP + (c ? (WP - 1) : 0)) * 64 + (size_t)o * 8;
            }
            *(h8*)(base + off) = z;
        }
    } else if (b < 8 + 1296) {
        // OIDHW fp32 -> [set][tap][co][ci swizzled] fp16 (B staged verbatim)
        int idx = (b - 8) * 256 + threadIdx.x;
        if (idx < 3 * 27 * 64 * 64) {
            int set = idx / 110592;
            int r = idx - set * 110592;
            const float* src = set == 0 ? W1 : (set == 1 ? W2 : W3);
            int ci = r & 63;
            int co = (r >> 6) & 63;
            int tap = r >> 12;
            int s = ci >> 3, j = ci & 7;
            wdst[set * 110592 + tap * 4096 + co * 64 + (((s ^ (co & 7)) << 3) | j)] =
                (_Float16)src[(co * 64 + ci) * 27 + tap];
        }
    } else {
        int v = (b - 1304) * 256 + threadIdx.x;
        if (v < nvox) {
            int d = coors[v * 4 + 1], h = coors[v * 4 + 2], w = coors[v * 4 + 3];
            atomicMax(&winner[(d * HH + h) * WW + w], v + 1);
        }
    }
}

__global__ __launch_bounds__(256) void scatter_k(const float* __restrict__ feat,
                                                 const int* __restrict__ coors,
                                                 const int* __restrict__ winner,
                                                 _Float16* __restrict__ A, int nvox) {
    int v = blockIdx.x * 4 + (threadIdx.x >> 6);
    int ci = threadIdx.x & 63;
    if (v >= nvox) return;
    int d = coors[v * 4 + 1], h = coors[v * 4 + 2], w = coors[v * 4 + 3];
    if (winner[(d * HH + h) * WW + w] != v + 1) return;
    int P = w + 1;
    int swz = (((ci >> 3) ^ (P & 7)) << 3) | (ci & 7);
    A[(size_t)d * SLICE + ((size_t)(h + 1) * WP + P) * 64 + swz] = (_Float16)feat[v * 64 + ci];
}

// ---------------- MFMA conv: r7 core, one-tap B phases, 3 blocks/CU --------
// Block = 4 waves; wave i -> output row h0+i, 48 px (mt=3), 64 co (nt=4).
// Per kd: stage A once (6 rows x 50 px, glds, swizzled); per tap t (9 of
// them): stage B one tap (8 glds instrs), barrier, 2 K32-steps x 12 MFMA.
// 3 co-resident blocks cover each other's barrier drains.
// mfma_f32_16x16x32_f16: A[m=lane&15][k=quad*8+j], D: co=lane&15, px=quad*4+reg
template <int FINAL>
__global__ __launch_bounds__(256, 3) void conv_mfma_k(
    const _Float16* __restrict__ in, void* __restrict__ outp,
    const _Float16* __restrict__ wt,
    const float* __restrict__ scale, const float* __restrict__ bias,
    int inD, int strideD, int padD) {
    __shared__ char smem_raw[LDS_TOTAL];
    _Float16* la = (_Float16*)smem_raw;
    _Float16* lb = (_Float16*)(smem_raw + LA_BYTES);

    const int lane = threadIdx.x & 63;
    const int wave = threadIdx.x >> 6;   // 0..3
    const int l16 = lane & 15;
    const int quad = lane >> 4;
    const int h0 = blockIdx.y * 4;
    const int wb = blockIdx.x * 48;      // 48 | 8 so (wb+px)&7 == px&7
    const int d = blockIdx.z;

    int kd_lo = padD - d * strideD; if (kd_lo < 0) kd_lo = 0;
    int kd_hi = inD - 1 - d * strideD + padD; if (kd_hi > 2) kd_hi = 2;

    f4 acc[3][4];
#pragma unroll
    for (int mt = 0; mt < 3; ++mt)
#pragma unroll
        for (int nt = 0; nt < 4; ++nt) acc[mt][nt] = (f4){0.f, 0.f, 0.f, 0.f};

    for (int kd = kd_lo; kd <= kd_hi; ++kd) {
        const int zd = d * strideD + kd - padD;
        const _Float16* __restrict__ aplane = in + (size_t)zd * SLICE;
        const _Float16* __restrict__ wkd = wt + (size_t)kd * 9 * 4096;

#pragma unroll
        for (int t = 0; t < 9; ++t) {    // tap = kh*3 + kw
            const int kh = t / 3;
            const int kw = t - 3 * kh;
            __syncthreads();             // prior phase's LDS reads complete
            if (t == 0) {
                // stage A: 6 rows x 50 px x 8 chunks = 2400 -> 38 instrs
                for (int j = wave; j < 38; j += 4) {
                    int c = j * 64 + lane;
                    if (c > 2399) c = 2399;            // dup into 512B pad
                    int r = c / 400;
                    int rem = c - r * 400;
                    int px = rem >> 3, s = rem & 7;
                    int g = wb + px; if (g > 177) g = 177;  // ragged edge dup
                    gl_lds16(aplane + ((size_t)(h0 + r) * WP + g) * 64 + s * 8,
                             smem_raw + j * 1024);
                }
            }
            // stage B: one tap, 64 co x 8 chunks = 512 -> 8 instrs (verbatim)
            {
                const _Float16* __restrict__ wp = wkd + t * 4096;
                for (int j = wave; j < 8; j += 4)
                    gl_lds16(wp + (j * 64 + lane) * 8, smem_raw + LA_BYTES + j * 1024);
            }
            __syncthreads();             // vmcnt drained: staged data visible

            // compute: 2 K32-steps x 12 MFMA
#pragma unroll
            for (int ch = 0; ch < 2; ++ch) {
                const int q = ch * 4 + quad;
                h8 b[4];
#pragma unroll
                for (int nt = 0; nt < 4; ++nt)
                    b[nt] = *(const h8*)(lb + (nt * 16 + l16) * 64 +
                                         ((q ^ (l16 & 7)) << 3));
#pragma unroll
                for (int mt = 0; mt < 3; ++mt) {
                    const int px = mt * 16 + l16 + kw;
                    h8 a = *(const h8*)(la + ((wave + kh) * 50 + px) * 64 +
                                        ((q ^ (px & 7)) << 3));
#pragma unroll
                    for (int nt = 0; nt < 4; ++nt)
                        acc[mt][nt] = __builtin_amdgcn_mfma_f32_16x16x32_f16(
                            a, b[nt], acc[mt][nt], 0, 0, 0);
                }
            }
        }
    }

    // epilogue: scale+bias+relu; D layout: co=l16(+nt*16), px=mt*16+quad*4+reg
    const int h = h0 + wave;
#pragma unroll
    for (int nt = 0; nt < 4; ++nt) {
        const int co = nt * 16 + l16;
        const float s = scale[co];
        const float bb = bias[co];
#pragma unroll
        for (int mt = 0; mt < 3; ++mt) {
            const int w0 = wb + mt * 16 + quad * 4;  // multiple of 4
            if (w0 < WW) {
                if (FINAL) {
                    f4 v;
#pragma unroll
                    for (int r = 0; r < 4; ++r) {
                        float x = acc[mt][nt][r] * s + bb;
                        v[r] = x > 0.f ? x : 0.f;
                    }
                    *(f4*)((float*)outp + (((size_t)(co * 2 + d)) * HH + h) * WW + w0) = v;
                } else {
#pragma unroll
                    for (int r = 0; r < 4; ++r) {
                        float x = acc[mt][nt][r] * s + bb;
                        x = x > 0.f ? x : 0.f;
                        const int P = w0 + r + 1;
                        const int swz = (((co >> 3) ^ (P & 7)) << 3) | (co & 7);
                        ((_Float16*)outp)[(size_t)d * SLICE +
                            ((size_t)(h + 1) * WP + P) * 64 + swz] = (_Float16)x;
                    }
                }
            }
        }
    }
}

// ---------------- launch ---------------------------------------------------
extern "C" void kernel_launch(void* const* d_in, const int* in_sizes, int n_in,
                              void* d_out, int out_size, void* d_ws, size_t ws_size,
                              hipStream_t stream) {
    const float* feat   = (const float*)d_in[0];
    const int*   coors  = (const int*)d_in[1];
    const float* W1     = (const float*)d_in[3];
    const float* scale1 = (const float*)d_in[4];
    const float* bias1  = (const float*)d_in[5];
    const float* W2     = (const float*)d_in[6];
    const float* scale2 = (const float*)d_in[7];
    const float* bias2  = (const float*)d_in[8];
    const float* W3     = (const float*)d_in[9];
    const float* scale3 = (const float*)d_in[10];
    const float* bias3  = (const float*)d_in[11];
    const int nvox = in_sizes[0] / 64;

    // workspace: [A1][win][A2][A3][wt x3]; memset covers A1+win only
    const size_t nA1 = (size_t)D_IN * SLICE;     // fp16 elems
    const size_t nWin = (size_t)D_IN * HH * WW;  // ints
    const size_t nA2 = (size_t)D1 * SLICE;
    const size_t nA3 = (size_t)D2 * SLICE;
    const size_t nWT = (size_t)27 * 64 * 64;     // fp16 elems per set

    _Float16* A1 = (_Float16*)d_ws;
    int* win = (int*)(A1 + nA1);
    _Float16* A2 = (_Float16*)(win + nWin);
    _Float16* A3 = A2 + nA2;
    _Float16* wt1 = A3 + nA3;
    _Float16* wt2 = wt1 + nWT;
    _Float16* wt3 = wt2 + nWT;

    hipMemsetAsync(d_ws, 0, nA1 * sizeof(_Float16) + nWin * sizeof(int), stream);

    const int win_blk = (nvox + 255) / 256;
    prep_k<<<8 + 1296 + win_blk, 256, 0, stream>>>(W1, W2, W3, wt1, A2, A3,
                                                   coors, win, nvox);
    scatter_k<<<(nvox + 3) / 4, 256, 0, stream>>>(feat, coors, win, A1, nvox);

    dim3 blk(256);
    // conv1: A1(10) -> A2(5)   (1000 blocks @ 3/CU)
    conv_mfma_k<0><<<dim3(4, 50, D1), blk, 0, stream>>>(A1, A2, wt1, scale1, bias1, D_IN, 2, 1);
    // conv2: A2(5) -> A3(3)    (600 blocks)
    conv_mfma_k<0><<<dim3(4, 50, D2), blk, 0, stream>>>(A2, A3, wt2, scale2, bias2, D1, 1, 0);
    // conv3: A3(3) -> out planar fp32 (float4 stores)  (400 blocks)
    conv_mfma_k<1><<<dim3(4, 50, D3), blk, 0, stream>>>(A3, (float*)d_out, wt3, scale3, bias3, D2, 2, 1);
}